// Round 7
// baseline (991.940 us; speedup 1.0000x reference)
//
#include <hip/hip_runtime.h>

// RGCN 2-layer: N=50000, E=800000, R=8, 64->64->32, fp32.
// R7 = R6 resubmit (container failure last round; kernel never ran).
//   memset(seg) -> hist(id = rel*NN+dst) -> 3-phase scan -> scatter ->
//   fused1: buf1 = [mean-agg_r(x)]@W1 + x@root1 + b1      (128-node tiles)
//   fused2: out  = [mean-agg_r(relu(buf1))]@W2 + relu(buf1)@root2 + b2
// Per phase r: block's rel-r edges are contiguous in perm; 4 waves consume the
// run cooperatively; per edge: broadcast perm word -> coalesced 256B feat row
// -> LDS atomicAdd into As[feat][dstlocal]. Compute: 8m x (TN/16)n per thread.

#define NN 50000
#define NE 800000
#define NR 8
#define NPR (NN * NR)              // 400000 segments (rel-major: id = r*NN+dst)
#define NBLK ((NPR + 1023) / 1024) // 391 scan blocks
#define BM 128                     // node tile
#define APAD 132                   // As row stride (16B-aligned, conflict-free)

// ---- per-(rel,dst) incoming-edge count into seg[] ---------------------------
__global__ __launch_bounds__(256) void k_hist(const int* __restrict__ dst,
                                              const int* __restrict__ et,
                                              int* __restrict__ seg) {
  int e = blockIdx.x * 256 + threadIdx.x;
  if (e < NE) atomicAdd(&seg[et[e] * NN + dst[e]], 1);
}

// ---- 3-phase exclusive scan of seg[NPR] (in place) --------------------------
__global__ __launch_bounds__(256) void k_scanA(const int* __restrict__ seg,
                                               int* __restrict__ bsum) {
  __shared__ int red[256];
  const int t = threadIdx.x;
  const int base = blockIdx.x * 1024 + t * 4;
  int s = 0;
#pragma unroll
  for (int j = 0; j < 4; ++j)
    if (base + j < NPR) s += seg[base + j];
  red[t] = s;
  __syncthreads();
  for (int off = 128; off > 0; off >>= 1) {
    if (t < off) red[t] += red[t + off];
    __syncthreads();
  }
  if (t == 0) bsum[blockIdx.x] = red[0];
}

__global__ __launch_bounds__(512) void k_scanB(const int* __restrict__ bsum,
                                               int* __restrict__ boff) {
  __shared__ int ps[512];
  const int t = threadIdx.x;
  const int v = (t < NBLK) ? bsum[t] : 0;
  ps[t] = v;
  __syncthreads();
  for (int off = 1; off < 512; off <<= 1) {
    int u = (t >= off) ? ps[t - off] : 0;
    __syncthreads();
    ps[t] += u;
    __syncthreads();
  }
  if (t < NBLK) boff[t] = ps[t] - v;  // exclusive
}

__global__ __launch_bounds__(256) void k_scanC(int* __restrict__ seg,
                                               const int* __restrict__ boff) {
  __shared__ int ps[256];
  const int t = threadIdx.x;
  const int base = blockIdx.x * 1024 + t * 4;
  int v[4];
  int s = 0;
#pragma unroll
  for (int j = 0; j < 4; ++j) {
    v[j] = (base + j < NPR) ? seg[base + j] : 0;
    s += v[j];
  }
  ps[t] = s;
  __syncthreads();
  for (int off = 1; off < 256; off <<= 1) {
    int u = (t >= off) ? ps[t - off] : 0;
    __syncthreads();
    ps[t] += u;
    __syncthreads();
  }
  int run = ps[t] - s + boff[blockIdx.x];
#pragma unroll
  for (int j = 0; j < 4; ++j) {
    if (base + j < NPR) {
      int old = v[j];
      seg[base + j] = run;  // exclusive prefix
      run += old;
    }
  }
}

// ---- scatter: perm sorted by (rel,dst); word = (src<<7)|(dst&127) -----------
// seg becomes inclusive segment ends.
__global__ __launch_bounds__(256) void k_scatter(const int* __restrict__ src,
                                                 const int* __restrict__ dst,
                                                 const int* __restrict__ et,
                                                 int* __restrict__ seg,
                                                 unsigned* __restrict__ perm) {
  int e = blockIdx.x * 256 + threadIdx.x;
  if (e < NE) {
    int pos = atomicAdd(&seg[et[e] * NN + dst[e]], 1);
    perm[pos] = ((unsigned)src[e] << 7) | ((unsigned)dst[e] & 127u);
  }
}

// ---- fused gather+GEMM ------------------------------------------------------
// 128-node tile, 9 phases (8 rels + root). As[k=64][m=BM (pad APAD)].
template <int TN, bool RELU>
__global__ __launch_bounds__(256) void k_fused(const float* __restrict__ feat,
                                               const unsigned* __restrict__ perm,
                                               const int* __restrict__ seg,
                                               const float* __restrict__ W,
                                               const float* __restrict__ root,
                                               const float* __restrict__ bias,
                                               float* __restrict__ C) {
  __shared__ float As[64][APAD];
  __shared__ float Bs[64][TN];
  __shared__ int   segl[BM + 1];
  const int tid  = threadIdx.x;
  const int n0   = blockIdx.x * BM;
  const int lane = tid & 63;
  const int wv   = tid >> 6;        // wave 0..3
  const int ty   = tid >> 4;        // 0..15 -> m-base ty*8
  const int tx   = tid & 15;        // 0..15 -> n-base tx*(TN/16)
  constexpr int JW = TN / 16;       // 4 | 2
  float acc[8][JW];
#pragma unroll
  for (int i = 0; i < 8; ++i)
#pragma unroll
    for (int j = 0; j < JW; ++j) acc[i][j] = 0.f;

  for (int kt = 0; kt < 9; ++kt) {
    __syncthreads();  // previous compute done before As/Bs/segl rewrite
    if (kt < 8) {
      // segment-bound strip: segl[t] = exclusive start of node n0+t under rel kt
      // = seg[kt*NN + n0 + t - 1]; only the GLOBAL first segment (g<0) is 0.
      if (tid < BM + 1) {
        int nn = n0 - 1 + tid;
        if (nn >= NN) nn = NN - 1;          // tail tile: empty segments
        const int g = kt * NN + nn;         // nn==-1 only when kt==0 && n0==0
        segl[tid] = (g < 0) ? 0 : seg[g];
      }
      // zero the accumulate tile
      float* AsF = &As[0][0];
      for (int i = tid; i < 64 * APAD; i += 256) AsF[i] = 0.f;
    }
    __syncthreads();

    if (kt < 8) {
      // ---- cooperative edge gather: LDS atomic accumulate ----
      const int lo = segl[0], hi = segl[BM];
      int e = lo + wv;
      for (; e + 4 < hi; e += 8) {
        const unsigned p0 = perm[e], p1 = perm[e + 4];
        float v0 = feat[(size_t)(p0 >> 7) * 64 + lane];
        float v1 = feat[(size_t)(p1 >> 7) * 64 + lane];
        if (RELU) { v0 = fmaxf(v0, 0.f); v1 = fmaxf(v1, 0.f); }
        atomicAdd(&As[lane][p0 & 127u], v0);
        atomicAdd(&As[lane][p1 & 127u], v1);
      }
      for (; e < hi; e += 4) {
        const unsigned p0 = perm[e];
        float v0 = feat[(size_t)(p0 >> 7) * 64 + lane];
        if (RELU) v0 = fmaxf(v0, 0.f);
        atomicAdd(&As[lane][p0 & 127u], v0);
      }
    } else {
      // ---- root phase: stage feat tile (transposed) ----
      for (int i = tid; i < BM * 64; i += 256) {
        const int k = i & 63, m = i >> 6;
        const int n = n0 + m;
        float v = (n < NN) ? feat[(size_t)n * 64 + k] : 0.f;
        if (RELU) v = fmaxf(v, 0.f);
        As[k][m] = v;
      }
    }
    // ---- stage B-tile: W[kt] (64 x TN) or root ----
    {
      const float* __restrict__ Bsrc = (kt < 8) ? (W + (size_t)kt * 64 * TN) : root;
      if (TN == 64) {
        const int kr = tid >> 4, lf = tid & 15;
#pragma unroll
        for (int pass = 0; pass < 4; ++pass) {
          const int k = kr + pass * 16;
          *(float4*)&Bs[k][lf * 4] = *(const float4*)&Bsrc[k * TN + lf * 4];
        }
      } else {
        const int kr = tid >> 3, lf = tid & 7;
#pragma unroll
        for (int pass = 0; pass < 2; ++pass) {
          const int k = kr + pass * 32;
          *(float4*)&Bs[k][lf * 4] = *(const float4*)&Bsrc[k * TN + lf * 4];
        }
      }
    }
    __syncthreads();

    // ---- per-column mean scale for this phase ----
    float invv[8];
#pragma unroll
    for (int i = 0; i < 8; ++i) {
      if (kt < 8) {
        const int m = ty * 8 + i;
        const int c = segl[m + 1] - segl[m];
        invv[i] = 1.0f / (float)(c < 1 ? 1 : c);
      } else {
        invv[i] = 1.0f;
      }
    }
    // ---- compute: 8m x JW n per thread ----
#pragma unroll 4
    for (int k = 0; k < 64; ++k) {
      float a[8], b[JW];
      *(float4*)&a[0] = *(const float4*)&As[k][ty * 8];
      *(float4*)&a[4] = *(const float4*)&As[k][ty * 8 + 4];
      if (TN == 64) {
        *(float4*)&b[0] = *(const float4*)&Bs[k][tx * 4];
      } else {
        *(float2*)&b[0] = *(const float2*)&Bs[k][tx * 2];
      }
      float af[8];
#pragma unroll
      for (int i = 0; i < 8; ++i) af[i] = a[i] * invv[i];
#pragma unroll
      for (int i = 0; i < 8; ++i)
#pragma unroll
        for (int j = 0; j < JW; ++j) acc[i][j] = fmaf(af[i], b[j], acc[i][j]);
    }
  }
  // ---- epilogue: + bias, store ----
  float bv[JW];
#pragma unroll
  for (int j = 0; j < JW; ++j) bv[j] = bias[tx * JW + j];
#pragma unroll
  for (int i = 0; i < 8; ++i) {
    const int n = n0 + ty * 8 + i;
    if (n < NN) {
#pragma unroll
      for (int j = 0; j < JW; ++j) acc[i][j] += bv[j];
      if (TN == 64) {
        *(float4*)&C[(size_t)n * 64 + tx * 4] = *(float4*)&acc[i][0];
      } else {
        *(float2*)&C[(size_t)n * 32 + tx * 2] = *(float2*)&acc[i][0];
      }
    }
  }
}

// =============================================================================
extern "C" void kernel_launch(void* const* d_in, const int* in_sizes, int n_in,
                              void* d_out, int out_size, void* d_ws, size_t ws_size,
                              hipStream_t stream) {
  const float* x     = (const float*)d_in[0];
  const int*   ei    = (const int*)d_in[1];
  const int*   et    = (const int*)d_in[2];
  const float* W1    = (const float*)d_in[3];
  const float* root1 = (const float*)d_in[4];
  const float* b1    = (const float*)d_in[5];
  const float* W2    = (const float*)d_in[6];
  const float* root2 = (const float*)d_in[7];
  const float* b2    = (const float*)d_in[8];
  float* out = (float*)d_out;
  const int* srcA = ei;
  const int* dstA = ei + NE;

  // ws layout (~18MB incl. buf1)
  char* w = (char*)d_ws;
  size_t off = 0;
  int*      seg  = (int*)(w + off);      off += (size_t)NPR * 4;   // 1.6MB
  int*      bsum = (int*)(w + off);      off += (size_t)NBLK * 4;
  int*      boff = (int*)(w + off);      off += (size_t)NBLK * 4;
  unsigned* perm = (unsigned*)(w + off); off += (size_t)NE * 4;    // 3.2MB
  off = (off + 15) & ~(size_t)15;
  float*    buf1 = (float*)(w + off);    off += (size_t)NN * 64 * 4; // 12.8MB

  hipMemsetAsync(seg, 0, (size_t)NPR * 4, stream);
  k_hist<<<(NE + 255) / 256, 256, 0, stream>>>(dstA, et, seg);
  k_scanA<<<NBLK, 256, 0, stream>>>(seg, bsum);
  k_scanB<<<1, 512, 0, stream>>>(bsum, boff);
  k_scanC<<<NBLK, 256, 0, stream>>>(seg, boff);
  k_scatter<<<(NE + 255) / 256, 256, 0, stream>>>(srcA, dstA, et, seg, perm);

  const int NB = (NN + BM - 1) / BM;  // 391
  k_fused<64, false><<<NB, 256, 0, stream>>>(x, perm, seg, W1, root1, b1, buf1);
  k_fused<32, true ><<<NB, 256, 0, stream>>>(buf1, perm, seg, W2, root2, b2, out);
}

// Round 8
// 437.656 us; speedup vs baseline: 2.2665x; 2.2665x over previous
//
#include <hip/hip_runtime.h>

// RGCN 2-layer: N=50000, E=800000, R=8, 64->64->32.
// R8: R3 separate-kernel structure (measured best) + bf16 bulk storage.
//   cvt(x->bf16) -> memset(seg) -> hist(id=dst*8+rel) -> 3-phase scan ->
//   scatter -> gath1(xbf -> A bf16, inv-scaled) ->
//   gemm1: hbf = bf16(relu([A|xbf]@vstack(W1,root1)+b1))   (fp32 acc, prefetch)
//   gath2(hbf -> A) -> gemm2: out = [A|hbf]@vstack(W2,root2)+b2 (fp32 out)
// All accumulation fp32; bf16 only for x/h/A storage. ws ~69MB.

#define NN 50000
#define NE 800000
#define NR 8
#define NPR (NN * NR)              // 400000 segments (dst-major: id = dst*8+r)
#define NBLK ((NPR + 1023) / 1024) // 391 scan blocks

__device__ __forceinline__ float b2f(unsigned u16) {
  return __uint_as_float(u16 << 16);
}
__device__ __forceinline__ unsigned short f2b(float f) {
  unsigned u = __float_as_uint(f);
  return (unsigned short)((u + 0x7fffu + ((u >> 16) & 1u)) >> 16);  // RNE
}

// ---- fp32 -> bf16 bulk convert (4 elems/thread) -----------------------------
__global__ __launch_bounds__(256) void k_cvt(const float* __restrict__ in,
                                             unsigned short* __restrict__ out,
                                             int n4) {
  int i = blockIdx.x * 256 + threadIdx.x;
  if (i < n4) {
    float4 v = ((const float4*)in)[i];
    ushort4 o;
    o.x = f2b(v.x); o.y = f2b(v.y); o.z = f2b(v.z); o.w = f2b(v.w);
    ((ushort4*)out)[i] = o;
  }
}

// ---- per-(dst,rel) incoming-edge count ------------------------------------
__global__ __launch_bounds__(256) void k_hist(const int* __restrict__ dst,
                                              const int* __restrict__ et,
                                              int* __restrict__ seg) {
  int e = blockIdx.x * 256 + threadIdx.x;
  if (e < NE) atomicAdd(&seg[dst[e] * NR + et[e]], 1);
}

// ---- 3-phase exclusive scan of seg[NPR] (in place) --------------------------
__global__ __launch_bounds__(256) void k_scanA(const int* __restrict__ seg,
                                               int* __restrict__ bsum) {
  __shared__ int red[256];
  const int t = threadIdx.x;
  const int base = blockIdx.x * 1024 + t * 4;
  int s = 0;
#pragma unroll
  for (int j = 0; j < 4; ++j)
    if (base + j < NPR) s += seg[base + j];
  red[t] = s;
  __syncthreads();
  for (int off = 128; off > 0; off >>= 1) {
    if (t < off) red[t] += red[t + off];
    __syncthreads();
  }
  if (t == 0) bsum[blockIdx.x] = red[0];
}

__global__ __launch_bounds__(512) void k_scanB(const int* __restrict__ bsum,
                                               int* __restrict__ boff) {
  __shared__ int ps[512];
  const int t = threadIdx.x;
  const int v = (t < NBLK) ? bsum[t] : 0;
  ps[t] = v;
  __syncthreads();
  for (int off = 1; off < 512; off <<= 1) {
    int u = (t >= off) ? ps[t - off] : 0;
    __syncthreads();
    ps[t] += u;
    __syncthreads();
  }
  if (t < NBLK) boff[t] = ps[t] - v;  // exclusive
}

__global__ __launch_bounds__(256) void k_scanC(int* __restrict__ seg,
                                               const int* __restrict__ boff) {
  __shared__ int ps[256];
  const int t = threadIdx.x;
  const int base = blockIdx.x * 1024 + t * 4;
  int v[4];
  int s = 0;
#pragma unroll
  for (int j = 0; j < 4; ++j) {
    v[j] = (base + j < NPR) ? seg[base + j] : 0;
    s += v[j];
  }
  ps[t] = s;
  __syncthreads();
  for (int off = 1; off < 256; off <<= 1) {
    int u = (t >= off) ? ps[t - off] : 0;
    __syncthreads();
    ps[t] += u;
    __syncthreads();
  }
  int run = ps[t] - s + boff[blockIdx.x];
#pragma unroll
  for (int j = 0; j < 4; ++j) {
    if (base + j < NPR) {
      int old = v[j];
      seg[base + j] = run;  // exclusive prefix
      run += old;
    }
  }
}

// ---- scatter: perm sorted by (dst,rel); seg becomes inclusive ends ----------
__global__ __launch_bounds__(256) void k_scatter(const int* __restrict__ src,
                                                 const int* __restrict__ dst,
                                                 const int* __restrict__ et,
                                                 int* __restrict__ seg,
                                                 int* __restrict__ perm) {
  int e = blockIdx.x * 256 + threadIdx.x;
  if (e < NE) {
    int pos = atomicAdd(&seg[dst[e] * NR + et[e]], 1);
    perm[pos] = src[e];
  }
}

// ---- gather: A[n, r*64..] = inv(n,r) * sum_e feat[src]  (bf16 in/out) -------
// wave per node; half-wave per edge (lane covers 2 feats via uint=2xbf16),
// 2 edges per half in flight (4 chains/wave).
__global__ __launch_bounds__(256) void k_gath(const unsigned short* __restrict__ feat,
                                              const int* __restrict__ perm,
                                              const int* __restrict__ seg,
                                              unsigned short* __restrict__ A) {
  const int lane = threadIdx.x & 63;
  const int n = blockIdx.x * 4 + ((int)threadIdx.x >> 6);
  if (n >= NN) return;
  const int half = lane >> 5, l32 = lane & 31;
  int b = 0;
  if (lane < 9) {
    const int g = n * NR - 1 + lane;
    b = (g < 0) ? 0 : seg[g];
  }
  const unsigned* __restrict__ f2 = (const unsigned*)feat;  // row = 32 uints
  unsigned* __restrict__ A2 = (unsigned*)A;                 // row = 256 uints
#pragma unroll
  for (int r = 0; r < NR; ++r) {
    const int s0 = __shfl(b, r);
    const int e0 = __shfl(b, r + 1);
    float a0 = 0.f, a1 = 0.f, c0 = 0.f, c1 = 0.f;
    int e = s0 + half;
    for (; e + 2 < e0; e += 4) {
      const unsigned p = (unsigned)perm[e];
      const unsigned q = (unsigned)perm[e + 2];
      const unsigned v = f2[(size_t)p * 32 + l32];
      const unsigned w = f2[(size_t)q * 32 + l32];
      a0 += b2f(v & 0xffffu); a1 += b2f(v >> 16);
      c0 += b2f(w & 0xffffu); c1 += b2f(w >> 16);
    }
    if (e < e0) {
      const unsigned p = (unsigned)perm[e];
      const unsigned v = f2[(size_t)p * 32 + l32];
      a0 += b2f(v & 0xffffu); a1 += b2f(v >> 16);
    }
    a0 += c0; a1 += c1;
    a0 += __shfl_down(a0, 32);
    a1 += __shfl_down(a1, 32);
    if (half == 0) {
      const int cnt = e0 - s0;
      const float inv = 1.0f / (float)(cnt < 1 ? 1 : cnt);
      const unsigned o = (unsigned)f2b(a0 * inv) | ((unsigned)f2b(a1 * inv) << 16);
      A2[(size_t)n * 256 + r * 32 + l32] = o;
    }
  }
}

// ---- GEMM: [A(bf16) 50k x 512 | rootsrc(bf16) 50k x 64] @ vstack(W,root) + b
// 64-node tile, 9 k-tiles, register prefetch (issue-early/write-late).
// OUTBF: write bf16(relu(.)) to Ch (layer 1); else fp32 to Cf (layer 2).
template <int TN, bool OUTBF>
__global__ __launch_bounds__(256) void k_gemm(const unsigned short* __restrict__ A,
                                              const unsigned short* __restrict__ rootsrc,
                                              const float* __restrict__ W,
                                              const float* __restrict__ root,
                                              const float* __restrict__ bias,
                                              float* __restrict__ Cf,
                                              unsigned short* __restrict__ Ch) {
  __shared__ float As[64][68];
  __shared__ float Bs[64][TN];
  const int tid = threadIdx.x;
  const int n0 = blockIdx.x * 64;
  const int ty = tid >> 4, tx = tid & 15;  // ty: also A-stage row, tx: k-chunk
  constexpr int JW = TN / 16;              // 4 | 2
  float acc[4][JW];
#pragma unroll
  for (int i = 0; i < 4; ++i)
#pragma unroll
    for (int j = 0; j < JW; ++j) acc[i][j] = 0.f;

  uint2 ar[4];
  float4 br[(TN == 64) ? 4 : 2];

  auto loadA = [&](int kt) {
#pragma unroll
    for (int p = 0; p < 4; ++p) {
      const int n = n0 + ty + p * 16;
      uint2 v = {0u, 0u};
      if (n < NN) {
        const unsigned short* s = (kt < 8)
            ? &A[(size_t)n * 512 + kt * 64 + tx * 4]
            : &rootsrc[(size_t)n * 64 + tx * 4];
        v = *(const uint2*)s;
      }
      ar[p] = v;
    }
  };
  auto loadB = [&](int kt) {
    const float* __restrict__ Bsrc = (kt < 8) ? (W + (size_t)kt * 64 * TN) : root;
    if (TN == 64) {
#pragma unroll
      for (int p = 0; p < 4; ++p)
        br[p] = *(const float4*)&Bsrc[((tid >> 4) + p * 16) * TN + (tid & 15) * 4];
    } else {
#pragma unroll
      for (int p = 0; p < 2; ++p)
        br[p] = *(const float4*)&Bsrc[((tid >> 3) + p * 32) * TN + (tid & 7) * 4];
    }
  };

  loadA(0);
  loadB(0);
  for (int kt = 0; kt < 9; ++kt) {
    // write staged regs to LDS
#pragma unroll
    for (int p = 0; p < 4; ++p) {
      const int mm = ty + p * 16;
      As[tx * 4 + 0][mm] = b2f(ar[p].x & 0xffffu);
      As[tx * 4 + 1][mm] = b2f(ar[p].x >> 16);
      As[tx * 4 + 2][mm] = b2f(ar[p].y & 0xffffu);
      As[tx * 4 + 3][mm] = b2f(ar[p].y >> 16);
    }
    if (TN == 64) {
#pragma unroll
      for (int p = 0; p < 4; ++p)
        *(float4*)&Bs[(tid >> 4) + p * 16][(tid & 15) * 4] = br[p];
    } else {
#pragma unroll
      for (int p = 0; p < 2; ++p)
        *(float4*)&Bs[(tid >> 3) + p * 32][(tid & 7) * 4] = br[p];
    }
    __syncthreads();
    if (kt < 8) { loadA(kt + 1); loadB(kt + 1); }  // prefetch under compute
#pragma unroll 8
    for (int k = 0; k < 64; ++k) {
      const float4 a = *(const float4*)&As[k][ty * 4];
      float bb[JW];
      if (TN == 64) {
        *(float4*)&bb[0] = *(const float4*)&Bs[k][tx * 4];
      } else {
        *(float2*)&bb[0] = *(const float2*)&Bs[k][tx * 2];
      }
      const float av[4] = {a.x, a.y, a.z, a.w};
#pragma unroll
      for (int i = 0; i < 4; ++i)
#pragma unroll
        for (int j = 0; j < JW; ++j) acc[i][j] = fmaf(av[i], bb[j], acc[i][j]);
    }
    __syncthreads();
  }
  // ---- epilogue ----
  float bv[JW];
#pragma unroll
  for (int j = 0; j < JW; ++j) bv[j] = bias[tx * JW + j];
#pragma unroll
  for (int i = 0; i < 4; ++i) {
    const int n = n0 + ty * 4 + i;
    if (n < NN) {
      if constexpr (OUTBF) {
        ushort4 o;
        o.x = f2b(fmaxf(acc[i][0] + bv[0], 0.f));
        o.y = f2b(fmaxf(acc[i][1] + bv[1], 0.f));
        o.z = f2b(fmaxf(acc[i][2] + bv[2], 0.f));
        o.w = f2b(fmaxf(acc[i][3] + bv[3], 0.f));
        *(ushort4*)&Ch[(size_t)n * 64 + tx * 4] = o;
      } else {
        float2 o;
        o.x = acc[i][0] + bv[0];
        o.y = acc[i][1] + bv[1];
        *(float2*)&Cf[(size_t)n * 32 + tx * 2] = o;
      }
    }
  }
}

// =============================================================================
extern "C" void kernel_launch(void* const* d_in, const int* in_sizes, int n_in,
                              void* d_out, int out_size, void* d_ws, size_t ws_size,
                              hipStream_t stream) {
  const float* x     = (const float*)d_in[0];
  const int*   ei    = (const int*)d_in[1];
  const int*   et    = (const int*)d_in[2];
  const float* W1    = (const float*)d_in[3];
  const float* root1 = (const float*)d_in[4];
  const float* b1    = (const float*)d_in[5];
  const float* W2    = (const float*)d_in[6];
  const float* root2 = (const float*)d_in[7];
  const float* b2    = (const float*)d_in[8];
  float* out = (float*)d_out;
  const int* srcA = ei;
  const int* dstA = ei + NE;

  // ws layout (~69MB)
  char* w = (char*)d_ws;
  size_t off = 0;
  int* seg  = (int*)(w + off); off += (size_t)NPR * 4;   // 1.6MB
  int* bsum = (int*)(w + off); off += (size_t)NBLK * 4;
  int* boff = (int*)(w + off); off += (size_t)NBLK * 4;
  off = (off + 15) & ~(size_t)15;
  int* perm = (int*)(w + off); off += (size_t)NE * 4;    // 3.2MB
  off = (off + 15) & ~(size_t)15;
  unsigned short* xbf = (unsigned short*)(w + off); off += (size_t)NN * 64 * 2; // 6.4MB
  off = (off + 15) & ~(size_t)15;
  unsigned short* hbf = (unsigned short*)(w + off); off += (size_t)NN * 64 * 2; // 6.4MB
  off = (off + 15) & ~(size_t)15;
  unsigned short* A = (unsigned short*)(w + off); off += (size_t)NN * 512 * 2;  // 51.2MB

  k_cvt<<<(NN * 64 / 4 + 255) / 256, 256, 0, stream>>>(x, xbf, NN * 64 / 4);
  hipMemsetAsync(seg, 0, (size_t)NPR * 4, stream);
  k_hist<<<(NE + 255) / 256, 256, 0, stream>>>(dstA, et, seg);
  k_scanA<<<NBLK, 256, 0, stream>>>(seg, bsum);
  k_scanB<<<1, 512, 0, stream>>>(bsum, boff);
  k_scanC<<<NBLK, 256, 0, stream>>>(seg, boff);
  k_scatter<<<(NE + 255) / 256, 256, 0, stream>>>(srcA, dstA, et, seg, perm);

  const int NB = (NN + 63) / 64;  // 782
  k_gath<<<(NN + 3) / 4, 256, 0, stream>>>(xbf, perm, seg, A);
  k_gemm<64, true ><<<NB, 256, 0, stream>>>(A, xbf, W1, root1, b1, nullptr, hbf);
  k_gath<<<(NN + 3) / 4, 256, 0, stream>>>(hbf, perm, seg, A);
  k_gemm<32, false><<<NB, 256, 0, stream>>>(A, hbf, W2, root2, b2, out, nullptr);
}

// Round 9
// 353.808 us; speedup vs baseline: 2.8036x; 1.2370x over previous
//
#include <hip/hip_runtime.h>

// RGCN 2-layer: N=50000, E=800000, R=8, 64->64->32.
// R9: R8 pipeline, but GEMMs -> LDS-free bf16 MFMA (16x16x32), weights
// pre-converted to bf16 and transposed: WT[col][k], k = rel*64+fin | 512+fin.
//   cvt(x->bf16), cvtW1, cvtW2 -> memset(seg) -> hist -> scan -> scatter ->
//   gath1(xbf->A) -> mfma1: hbf = bf16(relu([A|xbf]@WT1 + b1))
//   gath2(hbf->A) -> mfma2: out = [A|hbf]@WT2 + b2   (fp32)
// ws ~70MB.

#define NN 50000
#define NE 800000
#define NR 8
#define NPR (NN * NR)
#define NBLK ((NPR + 1023) / 1024)

typedef __attribute__((ext_vector_type(8))) short short8v;
typedef __attribute__((ext_vector_type(4))) float float4v;

__device__ __forceinline__ float b2f(unsigned u16) {
  return __uint_as_float(u16 << 16);
}
__device__ __forceinline__ unsigned short f2b(float f) {
  unsigned u = __float_as_uint(f);
  return (unsigned short)((u + 0x7fffu + ((u >> 16) & 1u)) >> 16);  // RNE
}

// ---- fp32 -> bf16 bulk convert (4 elems/thread) -----------------------------
__global__ __launch_bounds__(256) void k_cvt(const float* __restrict__ in,
                                             unsigned short* __restrict__ out,
                                             int n4) {
  int i = blockIdx.x * 256 + threadIdx.x;
  if (i < n4) {
    float4 v = ((const float4*)in)[i];
    ushort4 o;
    o.x = f2b(v.x); o.y = f2b(v.y); o.z = f2b(v.z); o.w = f2b(v.w);
    ((ushort4*)out)[i] = o;
  }
}

// ---- weights: WT[o][k] bf16, k<512: W[r=k>>6][fin=k&63][o]; else root[k-512][o]
__global__ __launch_bounds__(256) void k_cvtW(const float* __restrict__ W,
                                              const float* __restrict__ root,
                                              unsigned short* __restrict__ WT,
                                              int NOUT) {
  int i = blockIdx.x * 256 + threadIdx.x;
  if (i < NOUT * 576) {
    const int o = i / 576, k = i - o * 576;
    const float v = (k < 512)
        ? W[(size_t)(k >> 6) * 64 * NOUT + (size_t)(k & 63) * NOUT + o]
        : root[(size_t)(k - 512) * NOUT + o];
    WT[i] = f2b(v);
  }
}

// ---- per-(dst,rel) incoming-edge count --------------------------------------
__global__ __launch_bounds__(256) void k_hist(const int* __restrict__ dst,
                                              const int* __restrict__ et,
                                              int* __restrict__ seg) {
  int e = blockIdx.x * 256 + threadIdx.x;
  if (e < NE) atomicAdd(&seg[dst[e] * NR + et[e]], 1);
}

// ---- 3-phase exclusive scan of seg[NPR] (in place) --------------------------
__global__ __launch_bounds__(256) void k_scanA(const int* __restrict__ seg,
                                               int* __restrict__ bsum) {
  __shared__ int red[256];
  const int t = threadIdx.x;
  const int base = blockIdx.x * 1024 + t * 4;
  int s = 0;
#pragma unroll
  for (int j = 0; j < 4; ++j)
    if (base + j < NPR) s += seg[base + j];
  red[t] = s;
  __syncthreads();
  for (int off = 128; off > 0; off >>= 1) {
    if (t < off) red[t] += red[t + off];
    __syncthreads();
  }
  if (t == 0) bsum[blockIdx.x] = red[0];
}

__global__ __launch_bounds__(512) void k_scanB(const int* __restrict__ bsum,
                                               int* __restrict__ boff) {
  __shared__ int ps[512];
  const int t = threadIdx.x;
  const int v = (t < NBLK) ? bsum[t] : 0;
  ps[t] = v;
  __syncthreads();
  for (int off = 1; off < 512; off <<= 1) {
    int u = (t >= off) ? ps[t - off] : 0;
    __syncthreads();
    ps[t] += u;
    __syncthreads();
  }
  if (t < NBLK) boff[t] = ps[t] - v;  // exclusive
}

__global__ __launch_bounds__(256) void k_scanC(int* __restrict__ seg,
                                               const int* __restrict__ boff) {
  __shared__ int ps[256];
  const int t = threadIdx.x;
  const int base = blockIdx.x * 1024 + t * 4;
  int v[4];
  int s = 0;
#pragma unroll
  for (int j = 0; j < 4; ++j) {
    v[j] = (base + j < NPR) ? seg[base + j] : 0;
    s += v[j];
  }
  ps[t] = s;
  __syncthreads();
  for (int off = 1; off < 256; off <<= 1) {
    int u = (t >= off) ? ps[t - off] : 0;
    __syncthreads();
    ps[t] += u;
    __syncthreads();
  }
  int run = ps[t] - s + boff[blockIdx.x];
#pragma unroll
  for (int j = 0; j < 4; ++j) {
    if (base + j < NPR) {
      int old = v[j];
      seg[base + j] = run;  // exclusive prefix
      run += old;
    }
  }
}

// ---- scatter: perm sorted by (dst,rel); seg becomes inclusive ends ----------
__global__ __launch_bounds__(256) void k_scatter(const int* __restrict__ src,
                                                 const int* __restrict__ dst,
                                                 const int* __restrict__ et,
                                                 int* __restrict__ seg,
                                                 int* __restrict__ perm) {
  int e = blockIdx.x * 256 + threadIdx.x;
  if (e < NE) {
    int pos = atomicAdd(&seg[dst[e] * NR + et[e]], 1);
    perm[pos] = src[e];
  }
}

// ---- gather: A[n, r*64..] = inv(n,r) * sum_e feat[src]  (bf16 in/out) -------
__global__ __launch_bounds__(256) void k_gath(const unsigned short* __restrict__ feat,
                                              const int* __restrict__ perm,
                                              const int* __restrict__ seg,
                                              unsigned short* __restrict__ A) {
  const int lane = threadIdx.x & 63;
  const int n = blockIdx.x * 4 + ((int)threadIdx.x >> 6);
  if (n >= NN) return;
  const int half = lane >> 5, l32 = lane & 31;
  int b = 0;
  if (lane < 9) {
    const int g = n * NR - 1 + lane;
    b = (g < 0) ? 0 : seg[g];
  }
  const unsigned* __restrict__ f2 = (const unsigned*)feat;  // row = 32 uints
  unsigned* __restrict__ A2 = (unsigned*)A;                 // row = 256 uints
#pragma unroll
  for (int r = 0; r < NR; ++r) {
    const int s0 = __shfl(b, r);
    const int e0 = __shfl(b, r + 1);
    float a0 = 0.f, a1 = 0.f, c0 = 0.f, c1 = 0.f;
    int e = s0 + half;
    for (; e + 2 < e0; e += 4) {
      const unsigned p = (unsigned)perm[e];
      const unsigned q = (unsigned)perm[e + 2];
      const unsigned v = f2[(size_t)p * 32 + l32];
      const unsigned w = f2[(size_t)q * 32 + l32];
      a0 += b2f(v & 0xffffu); a1 += b2f(v >> 16);
      c0 += b2f(w & 0xffffu); c1 += b2f(w >> 16);
    }
    if (e < e0) {
      const unsigned p = (unsigned)perm[e];
      const unsigned v = f2[(size_t)p * 32 + l32];
      a0 += b2f(v & 0xffffu); a1 += b2f(v >> 16);
    }
    a0 += c0; a1 += c1;
    a0 += __shfl_down(a0, 32);
    a1 += __shfl_down(a1, 32);
    if (half == 0) {
      const int cnt = e0 - s0;
      const float inv = 1.0f / (float)(cnt < 1 ? 1 : cnt);
      const unsigned o = (unsigned)f2b(a0 * inv) | ((unsigned)f2b(a1 * inv) << 16);
      A2[(size_t)n * 256 + r * 32 + l32] = o;
    }
  }
}

// ---- MFMA GEMM: C[NN x TN] = [A | rootsrc] @ WT^T + bias --------------------
// LDS-free: every fragment is one 16B global load. Wave owns 16 rows;
// block = 4 waves = 64 rows. K = 576 = 18 steps of 32.
// A-frag: row = m0+(lane&15), k = kt*32+(lane>>4)*8. B-frag: col = f*16+(lane&15).
// C/D: col = lane&15, row = (lane>>4)*4 + j   [m89-verified].
template <int TN, bool OUTBF>
__global__ __launch_bounds__(256) void k_mfma(const unsigned short* __restrict__ A,
                                              const unsigned short* __restrict__ rootsrc,
                                              const unsigned short* __restrict__ WT,
                                              const float* __restrict__ bias,
                                              float* __restrict__ Cf,
                                              unsigned short* __restrict__ Ch) {
  constexpr int NF = TN / 16;  // 4 | 2
  const int lane = (int)(threadIdx.x & 63);
  const int wv   = (int)(threadIdx.x >> 6);
  const int m0   = blockIdx.x * 64 + wv * 16;
  const int rc   = lane & 15;
  const int kg   = (lane >> 4) * 8;
  int arow = m0 + rc;
  if (arow > NN - 1) arow = NN - 1;  // clamp (stores masked below)
  const unsigned short* __restrict__ ap = A + (size_t)arow * 512 + kg;
  const unsigned short* __restrict__ rp = rootsrc + (size_t)arow * 64 + kg;
  const unsigned short* __restrict__ wp = WT + (size_t)rc * 576 + kg;
  float4v acc[NF];
#pragma unroll
  for (int f = 0; f < NF; ++f) acc[f] = (float4v){0.f, 0.f, 0.f, 0.f};
#pragma unroll
  for (int kt = 0; kt < 18; ++kt) {
    short8v a;
    if (kt < 16) a = *(const short8v*)(ap + kt * 32);
    else         a = *(const short8v*)(rp + (kt - 16) * 32);
#pragma unroll
    for (int f = 0; f < NF; ++f) {
      const short8v b = *(const short8v*)(wp + (size_t)f * 16 * 576 + kt * 32);
      acc[f] = __builtin_amdgcn_mfma_f32_16x16x32_bf16(a, b, acc[f], 0, 0, 0);
    }
  }
  const int orow0 = m0 + (lane >> 4) * 4;
  const int col = lane & 15;
#pragma unroll
  for (int f = 0; f < NF; ++f) {
    const float bv = bias[f * 16 + col];
#pragma unroll
    for (int j = 0; j < 4; ++j) {
      const int r = orow0 + j;
      if (r < NN) {
        const float v = acc[f][j] + bv;
        if constexpr (OUTBF) {
          Ch[(size_t)r * 64 + f * 16 + col] = f2b(fmaxf(v, 0.f));
        } else {
          Cf[(size_t)r * 32 + f * 16 + col] = v;
        }
      }
    }
  }
}

// =============================================================================
extern "C" void kernel_launch(void* const* d_in, const int* in_sizes, int n_in,
                              void* d_out, int out_size, void* d_ws, size_t ws_size,
                              hipStream_t stream) {
  const float* x     = (const float*)d_in[0];
  const int*   ei    = (const int*)d_in[1];
  const int*   et    = (const int*)d_in[2];
  const float* W1    = (const float*)d_in[3];
  const float* root1 = (const float*)d_in[4];
  const float* b1    = (const float*)d_in[5];
  const float* W2    = (const float*)d_in[6];
  const float* root2 = (const float*)d_in[7];
  const float* b2    = (const float*)d_in[8];
  float* out = (float*)d_out;
  const int* srcA = ei;
  const int* dstA = ei + NE;

  // ws layout (~70MB)
  char* w = (char*)d_ws;
  size_t off = 0;
  int* seg  = (int*)(w + off); off += (size_t)NPR * 4;   // 1.6MB
  int* bsum = (int*)(w + off); off += (size_t)NBLK * 4;
  int* boff = (int*)(w + off); off += (size_t)NBLK * 4;
  off = (off + 15) & ~(size_t)15;
  int* perm = (int*)(w + off); off += (size_t)NE * 4;    // 3.2MB
  off = (off + 15) & ~(size_t)15;
  unsigned short* xbf = (unsigned short*)(w + off); off += (size_t)NN * 64 * 2; // 6.4MB
  off = (off + 15) & ~(size_t)15;
  unsigned short* hbf = (unsigned short*)(w + off); off += (size_t)NN * 64 * 2; // 6.4MB
  off = (off + 15) & ~(size_t)15;
  unsigned short* WT1 = (unsigned short*)(w + off); off += (size_t)64 * 576 * 2;
  off = (off + 15) & ~(size_t)15;
  unsigned short* WT2 = (unsigned short*)(w + off); off += (size_t)32 * 576 * 2;
  off = (off + 15) & ~(size_t)15;
  unsigned short* A = (unsigned short*)(w + off); off += (size_t)NN * 512 * 2;  // 51.2MB

  k_cvt<<<(NN * 64 / 4 + 255) / 256, 256, 0, stream>>>(x, xbf, NN * 64 / 4);
  k_cvtW<<<(64 * 576 + 255) / 256, 256, 0, stream>>>(W1, root1, WT1, 64);
  k_cvtW<<<(32 * 576 + 255) / 256, 256, 0, stream>>>(W2, root2, WT2, 32);
  hipMemsetAsync(seg, 0, (size_t)NPR * 4, stream);
  k_hist<<<(NE + 255) / 256, 256, 0, stream>>>(dstA, et, seg);
  k_scanA<<<NBLK, 256, 0, stream>>>(seg, bsum);
  k_scanB<<<1, 512, 0, stream>>>(bsum, boff);
  k_scanC<<<NBLK, 256, 0, stream>>>(seg, boff);
  k_scatter<<<(NE + 255) / 256, 256, 0, stream>>>(srcA, dstA, et, seg, perm);

  const int NBm = (NN + 63) / 64;  // 782
  k_gath<<<(NN + 3) / 4, 256, 0, stream>>>(xbf, perm, seg, A);
  k_mfma<64, true ><<<NBm, 256, 0, stream>>>(A, xbf, WT1, b1, nullptr, hbf);
  k_gath<<<(NN + 3) / 4, 256, 0, stream>>>(hbf, perm, seg, A);
  k_mfma<32, false><<<NBm, 256, 0, stream>>>(A, hbf, WT2, b2, out, nullptr);
}